// Round 9
// baseline (113.412 us; speedup 1.0000x reference)
//
#include <hip/hip_runtime.h>

#define N 4096
#define TSTEPS 3
#define FEAT 36
#define NVIS 6
#define HID 256
#define DIN 18   // TSTEPS*NVIS
#define DOUT 2
#define HT 2048  // half-tile of j staged in LDS (f32, transposed)

typedef __attribute__((ext_vector_type(8))) short bf16x8;   // 8 bf16 = 4 VGPR
typedef __attribute__((ext_vector_type(4))) float f32x4;

__device__ __forceinline__ short f2bf(float f) {
    unsigned u = __builtin_bit_cast(unsigned, f);
    unsigned r = (u + 0x7FFFu + ((u >> 16) & 1u)) >> 16;   // RNE
    return (short)r;
}

// ---------------- Prep: vis -> xallT[c][j] (transposed)  +  W1,W2 frags -----
__global__ void k_prep(const float* __restrict__ vis, const float* __restrict__ Wv,
                       const float* __restrict__ bv, float* __restrict__ xallT,
                       const float* __restrict__ W1, const float* __restrict__ W2,
                       short* __restrict__ Wp) {
    if (blockIdx.x < 288) {
        int o = blockIdx.x * 256 + threadIdx.x;   // 0..73727
        int c = o >> 12;                          // 0..17
        int j = o & 4095;
        int t  = c / NVIS;
        int cc = c - t * NVIS;
        const float* vrow = vis + (size_t)j * (TSTEPS * FEAT) + t * FEAT;
        float acc = bv[cc];
#pragma unroll
        for (int f = 0; f < FEAT; ++f) acc += vrow[f] * Wv[f * NVIS + cc];
        xallT[(size_t)c * N + j] = acc;           // coalesced along j
    } else {
        int t = (blockIdx.x - 288) * 256 + threadIdx.x;   // 0..131071
        int L  = t >> 16;
        int e  = t & 65535;
        int jj = e & 7;
        int l  = (e >> 3) & 63;
        int j  = (e >> 9) & 15;
        int s  = e >> 13;
        int k  = s * 32 + ((l >> 4) << 3) + jj;
        int n  = (j << 4) + (l & 15);
        const float* W = L ? W2 : W1;
        Wp[t] = f2bf(W[k * HID + n]);
    }
}

// One chunk of a-data: 2 rows x 12 consecutive floats (4 j's) per lane.
struct AChunk { float4 u0, u1, u2, v0, v1, v2; };

__device__ __forceinline__ AChunk aload(const float* __restrict__ a0,
                                        const float* __restrict__ a1,
                                        int lane, int g) {
    AChunk d;
    const size_t jb = (size_t)(g * 256 + lane * 4) * 3;
    const float4* p0 = (const float4*)(a0 + jb);
    const float4* p1 = (const float4*)(a1 + jb);
    d.u0 = p0[0]; d.u1 = p0[1]; d.u2 = p0[2];
    d.v0 = p1[0]; d.v1 = p1[1]; d.v2 = p1[2];
    return d;
}

// ---------------- Fused: LDS-transposed x + barrier-free stream + MLP tail --
// 512 blocks x 256 thr, 1 block/CU (147 KB LDS). Each wave owns 2 rows.
// x staged as xT[18][2048] f32: per chunk, each column is ONE conflict-free
// ds_read_b128 giving the lane's 4 j-values. a rides a 3-deep reg pipeline.
template<int FUSE>
__global__ __launch_bounds__(256, 1)
void k_msg_mlp(const float* __restrict__ a, const float* __restrict__ xallT,
               float* __restrict__ xagg,
               const short* __restrict__ Wp,
               const float* __restrict__ W0, const float* __restrict__ b0,
               const float* __restrict__ b1, const float* __restrict__ b2,
               const float* __restrict__ Wpf, const float* __restrict__ bp,
               float* __restrict__ u_out) {
    __shared__ union {
        float xT[DIN][HT];                    // 147456 B staged x half-table
        struct {
            float xa[8][DIN];                 // block's 8 xagg rows
            short hA[16 * 256];               // bf16 h, XOR-swizzled rows
            short hB[16 * 256];
            float h3[16 * 257];
        } m;                                  // 33408 B (aliased after stream)
    } sm;
    const int tid  = threadIdx.x;
    const int lane = tid & 63;
    const int wave = tid >> 6;
    const int row0 = blockIdx.x * 8;
    const int row_base = row0 + wave * 2;

    const float* a0 = a + (size_t)row_base       * (N * 3);
    const float* a1 = a + (size_t)(row_base + 1) * (N * 3);

    float acc[2][3][6];
    float s[2][2];
#pragma unroll
    for (int r = 0; r < 2; ++r) {
#pragma unroll
        for (int t = 0; t < 3; ++t)
#pragma unroll
            for (int c = 0; c < 6; ++c) acc[r][t][c] = 0.f;
        s[r][0] = 0.f; s[r][1] = 0.f;
    }

    // 3-deep a prefetch pipeline, global chunk index g = 0..15 (256 j each)
    AChunk p0 = aload(a0, a1, lane, 0);
    AChunk p1 = aload(a0, a1, lane, 1);
    AChunk p2 = aload(a0, a1, lane, 2);

#pragma unroll
    for (int g = 0; g < 16; ++g) {
        if ((g & 7) == 0) {               // (re)stage x half-table
            const int tile = g >> 3;
            __syncthreads();              // prior half's reads done
#pragma unroll
            for (int k = 0; k < 36; ++k) {
                int idx = tid + k * 256;          // 0..9215 float4s
                int c   = idx >> 9;               // 512 float4 per column
                int off = (idx & 511) << 2;
                *(float4*)&sm.xT[c][off] =
                    *(const float4*)&xallT[(size_t)c * N + tile * HT + off];
            }
            __syncthreads();
        }
        AChunk cur = p0; p0 = p1; p1 = p2;
        if (g + 3 < 16) p2 = aload(a0, a1, lane, g + 3);

        const float av0[4][3] = {{cur.u0.x,cur.u0.y,cur.u0.z},{cur.u0.w,cur.u1.x,cur.u1.y},
                                 {cur.u1.z,cur.u1.w,cur.u2.x},{cur.u2.y,cur.u2.z,cur.u2.w}};
        const float av1[4][3] = {{cur.v0.x,cur.v0.y,cur.v0.z},{cur.v0.w,cur.v1.x,cur.v1.y},
                                 {cur.v1.z,cur.v1.w,cur.v2.x},{cur.v2.y,cur.v2.z,cur.v2.w}};
        const int jb = (g & 7) * 256 + lane * 4;  // within staged half
#pragma unroll
        for (int t = 0; t < 3; ++t)
#pragma unroll
            for (int c = 0; c < 6; ++c) {
                float4 xv = *(const float4*)&sm.xT[t * 6 + c][jb];
                const float xq[4] = {xv.x, xv.y, xv.z, xv.w};
#pragma unroll
                for (int q = 0; q < 4; ++q) {
                    acc[0][t][c] += av0[q][t] * xq[q];
                    acc[1][t][c] += av1[q][t] * xq[q];
                }
            }
#pragma unroll
        for (int q = 0; q < 4; ++q) {
            s[0][0] += av0[q][1]; s[0][1] += av0[q][2];
            s[1][0] += av1[q][1]; s[1][1] += av1[q][2];
        }
    }

    // butterfly reduce (registers only)
#pragma unroll
    for (int m = 1; m < 64; m <<= 1) {
#pragma unroll
        for (int r = 0; r < 2; ++r) {
#pragma unroll
            for (int t = 0; t < 3; ++t)
#pragma unroll
                for (int c = 0; c < 6; ++c)
                    acc[r][t][c] += __shfl_xor(acc[r][t][c], m, 64);
            s[r][0] += __shfl_xor(s[r][0], m, 64);
            s[r][1] += __shfl_xor(s[r][1], m, 64);
        }
    }

    __syncthreads();   // ALL waves done reading xT before aliasing with m.*
    if (lane == 0) {
#pragma unroll
        for (int r = 0; r < 2; ++r) {
            const float s1 = s[r][0], s2 = s[r][1];
            float* xrow = sm.m.xa[wave * 2 + r];
#pragma unroll
            for (int c = 0; c < 6; ++c) {
                xrow[c]      = acc[r][2][c];
                xrow[6 + c]  = acc[r][1][c] * s2;
                xrow[12 + c] = acc[r][0][c] * s1 * s2;
            }
        }
    }
    __syncthreads();

    // coalesced xagg write (8 rows = 144 consecutive floats)
    for (int idx = tid; idx < 8 * DIN; idx += 256) {
        int r = idx / DIN, e = idx - r * DIN;
        xagg[(size_t)(row0 + r) * DIN + e] = sm.m.xa[r][e];
    }

    if (!FUSE) return;

    { // ---- layer 0 (K=18, f32 VALU): thread -> 1 row x 8 neurons ----
        const int row = tid >> 5;            // 0..7
        const int n0  = (tid & 31) * 8;
        float accv[8];
#pragma unroll
        for (int jn = 0; jn < 8; ++jn) accv[jn] = b0[n0 + jn];
        for (int k = 0; k < DIN; ++k) {
            float4 wa = *(const float4*)&W0[k * HID + n0];
            float4 wb = *(const float4*)&W0[k * HID + n0 + 4];
            const float w[8] = {wa.x,wa.y,wa.z,wa.w, wb.x,wb.y,wb.z,wb.w};
            float xr = sm.m.xa[row][k];
#pragma unroll
            for (int jn = 0; jn < 8; ++jn) accv[jn] += xr * w[jn];
        }
        bf16x8 v;
#pragma unroll
        for (int jn = 0; jn < 8; ++jn) v[jn] = f2bf(fmaxf(accv[jn], 0.f));
        *(bf16x8*)&sm.m.hA[(row * 256 + n0) ^ ((row & 7) << 3)] = v;
    }
    __syncthreads();

    // ---- layers 1 & 2: MFMA 16x16x32 bf16 (rows 8-15 garbage, confined) ----
    const int arow = lane & 15;
    const int kgrp = (lane >> 4) << 3;
    const int wv   = wave;
#pragma unroll 1
    for (int L = 0; L < 2; ++L) {
        const short* hsrc = L ? sm.m.hB : sm.m.hA;
        const float* bias = L ? b2 : b1;
        const short* WpL  = Wp + L * 65536;

        bf16x8 Af[8];
#pragma unroll
        for (int ks = 0; ks < 8; ++ks)
            Af[ks] = *(const bf16x8*)&hsrc[(arow * 256 + ks * 32 + kgrp) ^ ((arow & 7) << 3)];

        f32x4 c4[4];
#pragma unroll
        for (int jt = 0; jt < 4; ++jt) {
            float b = bias[wv * 64 + jt * 16 + (lane & 15)];
            c4[jt] = (f32x4){b, b, b, b};
        }
#pragma unroll
        for (int ks = 0; ks < 8; ++ks) {
#pragma unroll
            for (int jt = 0; jt < 4; ++jt) {
                int j = wv * 4 + jt;
                bf16x8 Bf = *(const bf16x8*)&WpL[(((ks * 16 + j) * 64) + lane) * 8];
                c4[jt] = __builtin_amdgcn_mfma_f32_16x16x32_bf16(Af[ks], Bf, c4[jt], 0, 0, 0);
            }
        }
#pragma unroll
        for (int jt = 0; jt < 4; ++jt) {
            int n = wv * 64 + jt * 16 + (lane & 15);
#pragma unroll
            for (int q = 0; q < 4; ++q) {
                int row = ((lane >> 4) << 2) + q;
                float v = fmaxf(c4[jt][q], 0.f);
                if (L == 0) sm.m.hB[(row * 256 + n) ^ ((row & 7) << 3)] = f2bf(v);
                else        sm.m.h3[row * 257 + n] = v;
            }
        }
        __syncthreads();
    }

    // ---- final layer 256 -> 2 for 8 rows: tid = r*16 + d*8 + ks ----
    if (tid < 128) {
        const int r  = tid >> 4;        // 0..7
        const int d  = (tid >> 3) & 1;
        const int ks = tid & 7;
        float accf = 0.f;
        const float* hr = &sm.m.h3[r * 257 + ks * 32];
#pragma unroll
        for (int i = 0; i < 32; ++i) accf += hr[i] * Wpf[(ks * 32 + i) * DOUT + d];
        accf += __shfl_xor(accf, 1, 64);
        accf += __shfl_xor(accf, 2, 64);
        accf += __shfl_xor(accf, 4, 64);
        if (ks == 0) u_out[(size_t)(row0 + r) * DOUT + d] = accf + bp[d];
    }
}

// ---------------- Fallback VALU MLP (only if workspace too small) -----------
#define HPITCH 20
__global__ __launch_bounds__(512, 2) void k_mlp(const float* __restrict__ xagg,
                      const float* __restrict__ W0, const float* __restrict__ b0,
                      const float* __restrict__ W1, const float* __restrict__ b1,
                      const float* __restrict__ W2, const float* __restrict__ b2,
                      const float* __restrict__ Wpf, const float* __restrict__ bp,
                      float* __restrict__ u_out) {
    __shared__ float xa[16][DIN];
    __shared__ float hb[2][HID][HPITCH];
    const int tid   = threadIdx.x;
    const int n     = tid & 255;
    const int rbase = (tid >> 8) * 8;
    const int base  = blockIdx.x * 16;

    for (int idx = tid; idx < 16 * DIN; idx += 512) {
        int r = idx / DIN, e = idx - r * DIN;
        xa[r][e] = xagg[(size_t)(base + r) * DIN + e];
    }
    __syncthreads();
    {
        float accv[8];
#pragma unroll
        for (int r = 0; r < 8; ++r) accv[r] = b0[n];
        for (int k = 0; k < DIN; ++k) {
            float w = W0[k * HID + n];
#pragma unroll
            for (int r = 0; r < 8; ++r) accv[r] += xa[rbase + r][k] * w;
        }
#pragma unroll
        for (int r = 0; r < 8; ++r) hb[0][n][rbase + r] = fmaxf(accv[r], 0.f);
    }
    __syncthreads();
    {
        float accv[8];
#pragma unroll
        for (int r = 0; r < 8; ++r) accv[r] = b1[n];
        for (int k = 0; k < HID; ++k) {
            float w = W1[k * HID + n];
            const float4* hp = (const float4*)&hb[0][k][rbase];
            float4 h0 = hp[0], h1 = hp[1];
            const float hv[8] = {h0.x,h0.y,h0.z,h0.w, h1.x,h1.y,h1.z,h1.w};
#pragma unroll
            for (int r = 0; r < 8; ++r) accv[r] += hv[r] * w;
        }
#pragma unroll
        for (int r = 0; r < 8; ++r) hb[1][n][rbase + r] = fmaxf(accv[r], 0.f);
    }
    __syncthreads();
    {
        float accv[8];
#pragma unroll
        for (int r = 0; r < 8; ++r) accv[r] = b2[n];
        for (int k = 0; k < HID; ++k) {
            float w = W2[k * HID + n];
            const float4* hp = (const float4*)&hb[1][k][rbase];
            float4 h0 = hp[0], h1 = hp[1];
            const float hv[8] = {h0.x,h0.y,h0.z,h0.w, h1.x,h1.y,h1.z,h1.w};
#pragma unroll
            for (int r = 0; r < 8; ++r) accv[r] += hv[r] * w;
        }
#pragma unroll
        for (int r = 0; r < 8; ++r) hb[0][n][rbase + r] = fmaxf(accv[r], 0.f);
    }
    __syncthreads();
    if (tid < 32) {
        int r = tid >> 1, d = tid & 1;
        float acc = bp[d];
        for (int k = 0; k < HID; ++k) acc += hb[0][k][r] * Wpf[k * DOUT + d];
        u_out[(size_t)(base + r) * DOUT + d] = acc;
    }
}

extern "C" void kernel_launch(void* const* d_in, const int* in_sizes, int n_in,
                              void* d_out, int out_size, void* d_ws, size_t ws_size,
                              hipStream_t stream) {
    const float* vis  = (const float*)d_in[0];
    const float* anet = (const float*)d_in[1];
    const float* Wv   = (const float*)d_in[2];
    const float* bv   = (const float*)d_in[3];
    const float* W0   = (const float*)d_in[4];
    const float* b0   = (const float*)d_in[5];
    const float* W1   = (const float*)d_in[6];
    const float* b1   = (const float*)d_in[7];
    const float* W2   = (const float*)d_in[8];
    const float* b2   = (const float*)d_in[9];
    const float* Wpf  = (const float*)d_in[10];
    const float* bp   = (const float*)d_in[11];

    float* xagg  = (float*)d_out;                  // 4096*18
    float* u_out = (float*)d_out + (size_t)N*DIN;  // 4096*2
    float* xallT = (float*)d_ws;                   // 18*4096 transposed (288 KB)
    short* Wpk   = (short*)((char*)d_ws + (512 << 10));  // 256 KB bf16 frags

    const bool fuse = ws_size >= (512 << 10) + 131072 * sizeof(short);

    if (fuse) {
        k_prep<<<800, 256, 0, stream>>>(vis, Wv, bv, xallT, W1, W2, Wpk);
        k_msg_mlp<1><<<N / 8, 256, 0, stream>>>(anet, xallT, xagg, Wpk,
                                                W0, b0, b1, b2, Wpf, bp, u_out);
    } else {
        k_prep<<<288, 256, 0, stream>>>(vis, Wv, bv, xallT, W1, W2, Wpk);
        k_msg_mlp<0><<<N / 8, 256, 0, stream>>>(anet, xallT, xagg, Wpk,
                                                W0, b0, b1, b2, Wpf, bp, u_out);
        k_mlp<<<N / 16, 512, 0, stream>>>(xagg, W0, b0, W1, b1, W2, b2, Wpf, bp, u_out);
    }
}